// Round 9
// baseline (390.943 us; speedup 1.0000x reference)
//
#include <hip/hip_runtime.h>
#include <math.h>

// SparseMoEALU via MFMA, BARRIER-FREE: bucket rows by opcode, ONE WAVE per 2
// same-op rows (16 M-rows). Zero __syncthreads: attention mixes only the 8
// positions within an input row, FFNs are row-local, so a 2-row tile is fully
// wave-local. fp32 master state lives in 16 REGISTERS/lane (FFN-GEMM2 and
// attn-PV share the same lane->(row,col) output mapping); the bf16 mirror Xb
// in per-wave LDS is the only shared medium (intra-wave lgkmcnt ordering).
// All fragment conventions are copied verbatim from the verified R8 kernel
// (swapped-operand FFN, separate Q/K, 8-row score slots, block-diag K=16 PV).

typedef __bf16 bfrag __attribute__((ext_vector_type(8)));
typedef __bf16 bhalf4 __attribute__((ext_vector_type(4)));
typedef float f32x4 __attribute__((ext_vector_type(4)));

#define MFMA16(a,b,c) __builtin_amdgcn_mfma_f32_16x16x32_bf16((a),(b),(c),0,0,0)

constexpr int NB = 16384, NOPS = 37, OP_START = 16;

// ws layout (int32 units for the bucketing region)
constexpr int WS_OPARR  = 0;        // 16384 ints; reused as tileArr after k_scatter
constexpr int WS_CNT    = 16384;
constexpr int WS_OFF    = 16448;    // 38 ints
constexpr int WS_CUR    = 16512;    // 37 ints
constexpr int WS_TB     = 16560;    // 38 ints (tile-base prefix, 2-row tiles)
constexpr int WS_ROWIDX = 16640;
constexpr int WS_INTS   = 33024;    // -> weight region at byte 132096

// bf16 element offsets inside weight region
constexpr int OFF_QKVT = 0;        // [192][64]
constexpr int OFF_WI1T = 12288;    // 37 x [128][64]
constexpr int OFF_WI2T = 315392;   // 37 x [64][128]
constexpr int OFF_WC1T = 618496;
constexpr int OFF_WC2T = 921600;
constexpr int OFF_WF1T = 1224704;
constexpr int OFF_WF2T = 1527808;
constexpr int OFF_WD1T = 1830912;  // 16 x [128][64]
constexpr int OFF_WD2T = 1961984;  // 16 x [64][128]
constexpr int OFF_WM1T = 2093056;
constexpr int OFF_WM2T = 2224128;

// ---------------- prep kernels ----------------

__global__ void k_op(const float* __restrict__ x, int* __restrict__ opArr, int* __restrict__ cnt) {
    int b = blockIdx.x * 64 + threadIdx.x;
    const float4* p = (const float4*)(x + (size_t)b * 512 + OP_START);
    float best = -1e30f; int op = 0;
    #pragma unroll
    for (int j = 0; j < 9; ++j) {
        float4 v = p[j];
        int k = j * 4;
        if (v.x > best) { best = v.x; op = k; }
        if (v.y > best) { best = v.y; op = k + 1; }
        if (v.z > best) { best = v.z; op = k + 2; }
        if (v.w > best) { best = v.w; op = k + 3; }
    }
    float last = x[(size_t)b * 512 + OP_START + 36];
    if (last > best) op = 36;
    opArr[b] = op;
    atomicAdd(&cnt[op], 1);
}

// dispatch priority rank: div/mod first, then carry ops, then the rest
__device__ __forceinline__ int rank_of(int o) {
    if (o == 3 || o == 4) return o - 3;          // 0,1
    if (o <= 2) return o + 2;                    // 2,3,4
    if (o >= 10 && o <= 13) return o - 5;        // 5..8
    if (o <= 9) return o + 4;                    // 9..13
    return o;                                    // 14..36
}

// wave-parallel scan: off[] op-ordered, tb[] 2-row-tile bases in priority
// order; also zeroes cur[].
__global__ void k_scan(const int* __restrict__ cnt, int* __restrict__ off,
                       int* __restrict__ tb, int* __restrict__ cur) {
    __shared__ int srt[64], pre[64];
    int t = threadIdx.x;  // 64 threads, one wave
    int c = (t < NOPS) ? cnt[t] : 0;
    int inc = c;
    #pragma unroll
    for (int d = 1; d < 64; d <<= 1) {
        int v = __shfl_up(inc, d);
        if (t >= d) inc += v;
    }
    if (t < NOPS) { off[t] = inc - c; cur[t] = 0; }
    if (t == NOPS - 1) off[NOPS] = inc;
    int tc = (c + 1) >> 1;
    srt[t] = 0;
    __syncthreads();
    if (t < NOPS) srt[rank_of(t)] = tc;
    __syncthreads();
    int s = srt[t];
    int sinc = s;
    #pragma unroll
    for (int d = 1; d < 64; d <<= 1) {
        int v = __shfl_up(sinc, d);
        if (t >= d) sinc += v;
    }
    pre[t] = sinc - s;
    if (t == 63) tb[NOPS] = sinc;
    __syncthreads();
    if (t < NOPS) tb[t] = pre[rank_of(t)];
}

// per-block LDS histogram -> 37 global atomics per block
__global__ void k_scatter(const int* __restrict__ opArr, const int* __restrict__ off,
                          int* __restrict__ cur, int* __restrict__ rowIdx) {
    __shared__ int h[NOPS], bb[NOPS];
    int tid = threadIdx.x;
    if (tid < NOPS) h[tid] = 0;
    __syncthreads();
    int b = blockIdx.x * 256 + tid;
    int op = opArr[b];
    int my = atomicAdd(&h[op], 1);
    __syncthreads();
    if (tid < NOPS && h[tid] > 0) bb[tid] = atomicAdd(&cur[tid], h[tid]);
    __syncthreads();
    rowIdx[off[op] + bb[op] + my] = b;
}

// tileArr[g] = (op<<16)|tile (aliases opArr; stream order protects)
__global__ void k_tilemap(const int* __restrict__ cnt, const int* __restrict__ tb,
                          int* __restrict__ tileArr) {
    int o = blockIdx.x;
    int n = (cnt[o] + 1) >> 1, base = tb[o];
    for (int t = threadIdx.x; t < n; t += 64)
        tileArr[base + t] = (o << 16) | t;
}

// transpose one [R][C] fp32 matrix -> [C][R] bf16 (289 blocks)
__global__ void k_wt(const float* __restrict__ Wi1, const float* __restrict__ Wi2,
                     const float* __restrict__ Wq,  const float* __restrict__ Wk,
                     const float* __restrict__ Wv,
                     const float* __restrict__ Wc1, const float* __restrict__ Wc2,
                     const float* __restrict__ Wd1, const float* __restrict__ Wd2,
                     const float* __restrict__ Wm1, const float* __restrict__ Wm2,
                     const float* __restrict__ Wf1, const float* __restrict__ Wf2,
                     __bf16* __restrict__ wb) {
    __shared__ float t[8320];  // max R*(C+1) = 128*65
    int m = blockIdx.x;
    const float* src; __bf16* dst; int R, C;
    if      (m < 37)  { src = Wi1 + m * 8192;        dst = wb + OFF_WI1T + m * 8192;        R = 64;  C = 128; }
    else if (m < 74)  { src = Wi2 + (m-37) * 8192;   dst = wb + OFF_WI2T + (m-37) * 8192;   R = 128; C = 64;  }
    else if (m < 111) { src = Wc1 + (m-74) * 8192;   dst = wb + OFF_WC1T + (m-74) * 8192;   R = 64;  C = 128; }
    else if (m < 148) { src = Wc2 + (m-111) * 8192;  dst = wb + OFF_WC2T + (m-111) * 8192;  R = 128; C = 64;  }
    else if (m < 185) { src = Wf1 + (m-148) * 8192;  dst = wb + OFF_WF1T + (m-148) * 8192;  R = 64;  C = 128; }
    else if (m < 222) { src = Wf2 + (m-185) * 8192;  dst = wb + OFF_WF2T + (m-185) * 8192;  R = 128; C = 64;  }
    else if (m < 238) { src = Wd1 + (m-222) * 8192;  dst = wb + OFF_WD1T + (m-222) * 8192;  R = 64;  C = 128; }
    else if (m < 254) { src = Wd2 + (m-238) * 8192;  dst = wb + OFF_WD2T + (m-238) * 8192;  R = 128; C = 64;  }
    else if (m < 270) { src = Wm1 + (m-254) * 8192;  dst = wb + OFF_WM1T + (m-254) * 8192;  R = 64;  C = 128; }
    else if (m < 286) { src = Wm2 + (m-270) * 8192;  dst = wb + OFF_WM2T + (m-270) * 8192;  R = 128; C = 64;  }
    else { const float* q3[3] = {Wq, Wk, Wv}; src = q3[m-286]; dst = wb + OFF_QKVT + (m-286) * 4096; R = 64; C = 64; }
    int n = R * C, Cp = C + 1;
    int logC = (C == 128) ? 7 : 6, logR = (R == 128) ? 7 : 6;
    for (int i = threadIdx.x; i < n; i += 256)
        t[(i >> logC) * Cp + (i & (C - 1))] = src[i];
    __syncthreads();
    for (int o = threadIdx.x; o < n; o += 256) {
        int c = o >> logR, r = o & (R - 1);
        dst[o] = (__bf16)t[r * Cp + c];
    }
}

// ---------------- main kernel helpers ----------------

__device__ __forceinline__ bfrag zfrag() {
    bfrag r;
    #pragma unroll
    for (int j = 0; j < 8; ++j) r[j] = (__bf16)0.0f;
    return r;
}

__device__ __forceinline__ bhalf4 pack4(f32x4 a) {
    bhalf4 r;
    r[0] = (__bf16)a[0]; r[1] = (__bf16)a[1]; r[2] = (__bf16)a[2]; r[3] = (__bf16)a[3];
    return r;
}

__device__ __forceinline__ bhalf4 pack4f(float4 a) {
    bhalf4 r;
    r[0] = (__bf16)a.x; r[1] = (__bf16)a.y; r[2] = (__bf16)a.z; r[3] = (__bf16)a.w;
    return r;
}

__device__ __forceinline__ bhalf4 pack4_relu(f32x4 a) {
    bhalf4 r;
    r[0] = (__bf16)fmaxf(a[0], 0.0f); r[1] = (__bf16)fmaxf(a[1], 0.0f);
    r[2] = (__bf16)fmaxf(a[2], 0.0f); r[3] = (__bf16)fmaxf(a[3], 0.0f);
    return r;
}

// Wave-local FFN on 16 M-rows (2 input rows). Swapped operands: D = W * X^T.
// GEMM1: all 8 nt by this wave; lane -> H[row lq][4 ch] (r8-verified mapping).
// GEMM2: all 4 nt; lane reg r -> Y[row lq][nt*16+qd*4+r], accumulated into the
// lane's register state st[nt], bf16 mirror written to Xb. NO barriers:
// intra-wave LDS write->read ordering via compiler lgkmcnt.
__device__ __forceinline__ void ffn_wave(float4* st, __bf16* Xb, __bf16* Hw,
    const __bf16* __restrict__ W1t, const float* __restrict__ b1,
    const __bf16* __restrict__ W2t, const float* __restrict__ b2,
    int lq, int qd) {
    bfrag xa0 = *(const bfrag*)&Xb[lq * 72 + qd * 8];
    bfrag xa1 = *(const bfrag*)&Xb[lq * 72 + 32 + qd * 8];
    #pragma unroll
    for (int nt = 0; nt < 8; ++nt) {
        float4 bv = *(const float4*)(b1 + nt * 16 + qd * 4);
        f32x4 acc = {bv.x, bv.y, bv.z, bv.w};
        acc = MFMA16(*(const bfrag*)(W1t + (nt * 16 + lq) * 64 + qd * 8),      xa0, acc);
        acc = MFMA16(*(const bfrag*)(W1t + (nt * 16 + lq) * 64 + 32 + qd * 8), xa1, acc);
        *(bhalf4*)&Hw[lq * 136 + nt * 16 + qd * 4] = pack4_relu(acc);
    }
    bfrag h[4];
    #pragma unroll
    for (int kf = 0; kf < 4; ++kf)
        h[kf] = *(const bfrag*)&Hw[lq * 136 + kf * 32 + qd * 8];
    #pragma unroll
    for (int nt = 0; nt < 4; ++nt) {
        float4 bv = *(const float4*)(b2 + nt * 16 + qd * 4);
        f32x4 acc = {bv.x, bv.y, bv.z, bv.w};
        #pragma unroll
        for (int kf = 0; kf < 4; ++kf)
            acc = MFMA16(*(const bfrag*)(W2t + (nt * 16 + lq) * 128 + kf * 32 + qd * 8), h[kf], acc);
        st[nt].x += acc[0]; st[nt].y += acc[1]; st[nt].z += acc[2]; st[nt].w += acc[3];
        *(bhalf4*)&Xb[lq * 72 + nt * 16 + qd * 4] = pack4f(st[nt]);
    }
}

// Wave-local attention on 2 input rows (16 M-rows = 16 positions). r8's chunk
// code with both halves executed sequentially by the same wave. Slots: half 0
// = positions 0..7 (input row 0), half 1 = 8..15 (input row 1). Scores A/B
// fragment rows use ((half*8+lq)&15): rows 8..15 of the fragment are garbage
// and discarded (only qd<2 / q-row<8 kept) — r8's exact valid-lane rule.
__device__ __forceinline__ void attn_wave(float4* st, __bf16* Xb, __bf16* Qb,
    __bf16* Kb, __bf16* VtT, __bf16* Pb, const __bf16* __restrict__ qkvt,
    int lq, int qd) {
    bfrag xa0 = *(const bfrag*)&Xb[lq * 72 + qd * 8];
    bfrag xa1 = *(const bfrag*)&Xb[lq * 72 + 32 + qd * 8];
    // QKV projection: all 12 nt by this wave (Q nt0-3 / K nt4-7 swapped,
    // V nt8-11 unswapped -> V^T[ch][pos]); r8-verified stores.
    #pragma unroll
    for (int nt = 0; nt < 12; ++nt) {
        bfrag w0 = *(const bfrag*)(qkvt + (nt * 16 + lq) * 64 + qd * 8);
        bfrag w1 = *(const bfrag*)(qkvt + (nt * 16 + lq) * 64 + 32 + qd * 8);
        f32x4 acc = {0.f, 0.f, 0.f, 0.f};
        if (nt < 8) {
            acc = MFMA16(w0, xa0, acc);
            acc = MFMA16(w1, xa1, acc);
            __bf16* dst = (nt < 4)
                ? &Qb[lq * 80 + nt * 16 + qd * 4]
                : &Kb[lq * 80 + (nt - 4) * 16 + qd * 4];
            *(bhalf4*)dst = pack4(acc);
        } else {
            acc = MFMA16(xa0, w0, acc);
            acc = MFMA16(xa1, w1, acc);
            *(bhalf4*)&VtT[((nt - 8) * 16 + lq) * 16 + qd * 4] = pack4(acc);
        }
    }
    // scores + softmax per 8-row slot
    #pragma unroll
    for (int half = 0; half < 2; ++half) {
        int qr = (half * 8 + lq) & 15;
        f32x4 sv = {0.f, 0.f, 0.f, 0.f};
        #pragma unroll
        for (int kf = 0; kf < 2; ++kf) {
            bfrag qa = *(const bfrag*)&Qb[qr * 80 + kf * 32 + qd * 8];
            bfrag kb = *(const bfrag*)&Kb[qr * 80 + kf * 32 + qd * 8];
            sv = MFMA16(qa, kb, sv);
        }
        // valid S at qd<2 (q-row qd*4+r), lq<8 (k-col); reduce across 8 k-lanes
        float p4[4];
        #pragma unroll
        for (int r = 0; r < 4; ++r) {
            float v = sv[r] * 0.125f;
            float m = v;
            m = fmaxf(m, __shfl_xor(m, 1));
            m = fmaxf(m, __shfl_xor(m, 2));
            m = fmaxf(m, __shfl_xor(m, 4));
            float e = __expf(v - m);
            float s = e;
            s += __shfl_xor(s, 1);
            s += __shfl_xor(s, 2);
            s += __shfl_xor(s, 4);
            p4[r] = e * __builtin_amdgcn_rcpf(s);
        }
        if (lq < 8 && qd < 2) {
            #pragma unroll
            for (int r = 0; r < 4; ++r)
                Pb[(half * 8 + qd * 4 + r) * 16 + half * 8 + lq] = (__bf16)p4[r];
        }
    }
    // PV: O += P_blkdiag @ V over all 16 rows; K=16 (qd>=2 lanes -> zfrag)
    bfrag pb = (qd < 2) ? *(const bfrag*)&Pb[lq * 16 + qd * 8] : zfrag();
    #pragma unroll
    for (int nt = 0; nt < 4; ++nt) {
        bfrag va = (qd < 2) ? *(const bfrag*)&VtT[(nt * 16 + lq) * 16 + qd * 8]
                            : zfrag();
        f32x4 z = {0.f, 0.f, 0.f, 0.f};
        f32x4 acc = MFMA16(va, pb, z);
        st[nt].x += acc[0]; st[nt].y += acc[1]; st[nt].z += acc[2]; st[nt].w += acc[3];
        *(bhalf4*)&Xb[lq * 72 + nt * 16 + qd * 4] = pack4f(st[nt]);
    }
}

// ---------------- main kernel ----------------

__global__ void __launch_bounds__(256, 4)
moe_main(const float* __restrict__ x, float* __restrict__ out,
         const int* __restrict__ tileArr, const int* __restrict__ tb,
         const int* __restrict__ cnt, const int* __restrict__ off,
         const int* __restrict__ rowIdx, const __bf16* __restrict__ wb,
         const float* __restrict__ bi1, const float* __restrict__ bi2,
         const float* __restrict__ bc1, const float* __restrict__ bc2,
         const float* __restrict__ bd1, const float* __restrict__ bd2,
         const float* __restrict__ bm1, const float* __restrict__ bm2,
         const float* __restrict__ bf1_, const float* __restrict__ bf2_) {
    // per-wave LDS slices; waves never share -> NO __syncthreads anywhere.
    // per-wave layout (9984 B): Hw [0,4352) overlaps Qb [0,2560)+Kb[2560,5120);
    // VtT [5120,7168); Pb [7168,7680) (survives FFN: outside Hw); Xb [7680,9984)
    __shared__ __align__(16) unsigned char UB[4 * 9984];
    int tid = threadIdx.x;
    int w = tid >> 6, lane = tid & 63, lq = lane & 15, qd = lane >> 4;
    unsigned char* S = UB + w * 9984;
    __bf16* Hw  = (__bf16*)S;
    __bf16* Qb  = (__bf16*)S;
    __bf16* Kb  = (__bf16*)(S + 2560);
    __bf16* VtT = (__bf16*)(S + 5120);
    __bf16* Pb  = (__bf16*)(S + 7168);
    __bf16* Xb  = (__bf16*)(S + 7680);

    int t4 = blockIdx.x * 4 + w;
    if (t4 >= tb[NOPS]) return;           // per-wave exit: safe, no barriers
    int v = tileArr[t4];
    int op = v >> 16, tile = v & 0xffff;

    int base = off[op] + tile * 2;
    int n2 = cnt[op] - tile * 2; if (n2 > 2) n2 = 2;
    int r0 = rowIdx[base];
    int r1 = rowIdx[base + (n2 > 1 ? 1 : 0)];

    // register-resident fp32 state: lane owns X[row lq][cols nt*16+qd*4..+3]
    float4 st[4];
    {
        const float* xr = x + (size_t)(lq < 8 ? r0 : r1) * 512 + (lq & 7) * 64;
        #pragma unroll
        for (int nt = 0; nt < 4; ++nt) {
            st[nt] = *(const float4*)(xr + nt * 16 + qd * 4);
            *(bhalf4*)&Xb[lq * 72 + nt * 16 + qd * 4] = pack4f(st[nt]);
        }
    }

    bool carry = (op <= 2) || (op >= 10 && op <= 13);
    if (carry) {
        // one-time zero of Pb (off-diag quadrants stay zero; diag blocks
        // rewritten every iter; Pb is outside Hw so it survives FFN phases)
        bhalf4 z4; z4[0] = (__bf16)0.f; z4[1] = (__bf16)0.f; z4[2] = (__bf16)0.f; z4[3] = (__bf16)0.f;
        *(bhalf4*)&Pb[lane * 4] = z4;
    }

    // Stage 1: initial experts
    ffn_wave(st, Xb, Hw, wb + OFF_WI1T + op * 8192, bi1 + op * 128,
                         wb + OFF_WI2T + op * 8192, bi2 + op * 64, lq, qd);

    // Stages 2-3: carry cascade
    if (carry) {
        const __bf16* qkvt = wb + OFF_QKVT;
        for (int it = 0; it < 7; ++it) {
            attn_wave(st, Xb, Qb, Kb, VtT, Pb, qkvt, lq, qd);
            ffn_wave(st, Xb, Hw, wb + OFF_WC1T + op * 8192, bc1 + op * 128,
                                 wb + OFF_WC2T + op * 8192, bc2 + op * 64, lq, qd);
        }
    }
    // DIV / MOD iterative FFNs
    if (op == 3) {
        for (int i = 0; i < 16; ++i)
            ffn_wave(st, Xb, Hw, wb + OFF_WD1T + i * 8192, bd1 + i * 128,
                                 wb + OFF_WD2T + i * 8192, bd2 + i * 64, lq, qd);
    }
    if (op == 4) {
        for (int i = 0; i < 16; ++i)
            ffn_wave(st, Xb, Hw, wb + OFF_WM1T + i * 8192, bm1 + i * 128,
                                 wb + OFF_WM2T + i * 8192, bm2 + i * 64, lq, qd);
    }
    // Stage 4: final experts
    ffn_wave(st, Xb, Hw, wb + OFF_WF1T + op * 8192, bf1_ + op * 128,
                         wb + OFF_WF2T + op * 8192, bf2_ + op * 64, lq, qd);

    // store from registers (skip duplicate half when n2 == 1)
    if (lq < 8 || n2 > 1) {
        float* orow = out + (size_t)(lq < 8 ? r0 : r1) * 512 + (lq & 7) * 64;
        #pragma unroll
        for (int nt = 0; nt < 4; ++nt)
            *(float4*)(orow + nt * 16 + qd * 4) = st[nt];
    }
}

// ---------------- launch ----------------

extern "C" void kernel_launch(void* const* d_in, const int* in_sizes, int n_in,
                              void* d_out, int out_size, void* d_ws, size_t ws_size,
                              hipStream_t stream) {
    (void)in_sizes; (void)n_in; (void)out_size; (void)ws_size;
    const float* x   = (const float*)d_in[0];
    const float* Wi1 = (const float*)d_in[1];
    const float* bi1 = (const float*)d_in[2];
    const float* Wi2 = (const float*)d_in[3];
    const float* bi2 = (const float*)d_in[4];
    const float* Wq  = (const float*)d_in[5];
    const float* Wk  = (const float*)d_in[6];
    const float* Wv  = (const float*)d_in[7];
    const float* Wc1 = (const float*)d_in[8];
    const float* bc1 = (const float*)d_in[9];
    const float* Wc2 = (const float*)d_in[10];
    const float* bc2 = (const float*)d_in[11];
    const float* Wd1 = (const float*)d_in[12];
    const float* bd1 = (const float*)d_in[13];
    const float* Wd2 = (const float*)d_in[14];
    const float* bd2 = (const float*)d_in[15];
    const float* Wm1 = (const float*)d_in[16];
    const float* bm1 = (const float*)d_in[17];
    const float* Wm2 = (const float*)d_in[18];
    const float* bm2 = (const float*)d_in[19];
    const float* Wf1 = (const float*)d_in[20];
    const float* bf1 = (const float*)d_in[21];
    const float* Wf2 = (const float*)d_in[22];
    const float* bf2 = (const float*)d_in[23];
    float* out = (float*)d_out;

    int* wsi     = (int*)d_ws;
    int* opArr   = wsi + WS_OPARR;
    int* tileArr = wsi + WS_OPARR;   // alias: written after k_scatter consumes opArr
    int* cnt     = wsi + WS_CNT;
    int* off     = wsi + WS_OFF;
    int* cur     = wsi + WS_CUR;
    int* tb      = wsi + WS_TB;
    int* rowIdx  = wsi + WS_ROWIDX;
    __bf16* wb   = (__bf16*)((char*)d_ws + WS_INTS * 4);

    hipMemsetAsync((char*)d_ws + WS_CNT * 4, 0, NOPS * 4, stream);
    k_op<<<NB / 64, 64, 0, stream>>>(x, opArr, cnt);
    k_scan<<<1, 64, 0, stream>>>(cnt, off, tb, cur);
    k_scatter<<<NB / 256, 256, 0, stream>>>(opArr, off, cur, rowIdx);
    k_tilemap<<<NOPS, 64, 0, stream>>>(cnt, tb, tileArr);
    k_wt<<<289, 256, 0, stream>>>(Wi1, Wi2, Wq, Wk, Wv, Wc1, Wc2, Wd1, Wd2, Wm1, Wm2, Wf1, Wf2, wb);
    int grid = (NB / 2 + NOPS + 3) / 4 + 1;
    moe_main<<<grid, 256, 0, stream>>>(x, out, tileArr, tb, cnt, off, rowIdx, wb,
                                       bi1, bi2, bc1, bc2, bd1, bd2, bm1, bm2, bf1, bf2);
}

// Round 12
// 255.998 us; speedup vs baseline: 1.5271x; 1.5271x over previous
//
#include <hip/hip_runtime.h>
#include <math.h>

// SparseMoEALU via MFMA: bucket 16384 rows by opcode, one 4-wave block per 4
// same-op rows (M=32). All GEMMs use SWAPPED MFMA operands (D = W * X^T).
// State: fp32 Xs + bf16 mirror Xb in LDS (R8). R11 (resubmit; round 11 was an
// infra failure, no kernel signal):
//  (a) FUSED scores+softmax+PV: P is wave-local (Pb write -> immediate read,
//      r9-validated lgkmcnt ordering; PV RMW row-predicated per slot) ->
//      attn barriers 3 -> 2, carry-iter barriers 5 -> 4.
//  (b) LDS stride padding: Qb/Kb 80 -> 72 elems, VtT 16 -> 24 elems
//      (4-way -> 2-way bank aliasing on the scores/PV b128 reads).

typedef __bf16 bfrag __attribute__((ext_vector_type(8)));
typedef __bf16 bhalf4 __attribute__((ext_vector_type(4)));
typedef float f32x4 __attribute__((ext_vector_type(4)));

#define MFMA16(a,b,c) __builtin_amdgcn_mfma_f32_16x16x32_bf16((a),(b),(c),0,0,0)

constexpr int NB = 16384, NOPS = 37, OP_START = 16;

// ws layout (int32 units for the bucketing region)
constexpr int WS_OPARR  = 0;        // 16384 ints; reused as tileArr after k_scatter
constexpr int WS_CNT    = 16384;
constexpr int WS_OFF    = 16448;    // 38 ints
constexpr int WS_CUR    = 16512;    // 37 ints
constexpr int WS_TB     = 16560;    // 38 ints (tile-base prefix)
constexpr int WS_ROWIDX = 16640;
constexpr int WS_INTS   = 33024;    // -> weight region at byte 132096

// bf16 element offsets inside weight region
constexpr int OFF_QKVT = 0;        // [192][64]
constexpr int OFF_WI1T = 12288;    // 37 x [128][64]
constexpr int OFF_WI2T = 315392;   // 37 x [64][128]
constexpr int OFF_WC1T = 618496;
constexpr int OFF_WC2T = 921600;
constexpr int OFF_WF1T = 1224704;
constexpr int OFF_WF2T = 1527808;
constexpr int OFF_WD1T = 1830912;  // 16 x [128][64]
constexpr int OFF_WD2T = 1961984;  // 16 x [64][128]
constexpr int OFF_WM1T = 2093056;
constexpr int OFF_WM2T = 2224128;

// ---------------- prep kernels ----------------

__global__ void k_op(const float* __restrict__ x, int* __restrict__ opArr, int* __restrict__ cnt) {
    int b = blockIdx.x * 64 + threadIdx.x;
    const float4* p = (const float4*)(x + (size_t)b * 512 + OP_START);
    float best = -1e30f; int op = 0;
    #pragma unroll
    for (int j = 0; j < 9; ++j) {
        float4 v = p[j];
        int k = j * 4;
        if (v.x > best) { best = v.x; op = k; }
        if (v.y > best) { best = v.y; op = k + 1; }
        if (v.z > best) { best = v.z; op = k + 2; }
        if (v.w > best) { best = v.w; op = k + 3; }
    }
    float last = x[(size_t)b * 512 + OP_START + 36];
    if (last > best) op = 36;
    opArr[b] = op;
    atomicAdd(&cnt[op], 1);
}

// dispatch priority rank: div/mod first, then carry ops, then the rest
__device__ __forceinline__ int rank_of(int o) {
    if (o == 3 || o == 4) return o - 3;          // 0,1
    if (o <= 2) return o + 2;                    // 2,3,4
    if (o >= 10 && o <= 13) return o - 5;        // 5..8
    if (o <= 9) return o + 4;                    // 9..13
    return o;                                    // 14..36
}

// wave-parallel scan: off[] op-ordered, tb[] tile-bases in priority order;
// also zeroes cur[].
__global__ void k_scan(const int* __restrict__ cnt, int* __restrict__ off,
                       int* __restrict__ tb, int* __restrict__ cur) {
    __shared__ int srt[64], pre[64];
    int t = threadIdx.x;  // 64 threads, one wave
    int c = (t < NOPS) ? cnt[t] : 0;
    int inc = c;
    #pragma unroll
    for (int d = 1; d < 64; d <<= 1) {
        int v = __shfl_up(inc, d);
        if (t >= d) inc += v;
    }
    if (t < NOPS) { off[t] = inc - c; cur[t] = 0; }
    if (t == NOPS - 1) off[NOPS] = inc;
    int tc = (c + 3) >> 2;
    srt[t] = 0;
    __syncthreads();
    if (t < NOPS) srt[rank_of(t)] = tc;
    __syncthreads();
    int s = srt[t];
    int sinc = s;
    #pragma unroll
    for (int d = 1; d < 64; d <<= 1) {
        int v = __shfl_up(sinc, d);
        if (t >= d) sinc += v;
    }
    pre[t] = sinc - s;
    if (t == 63) tb[NOPS] = sinc;
    __syncthreads();
    if (t < NOPS) tb[t] = pre[rank_of(t)];
}

// per-block LDS histogram -> 37 global atomics per block
__global__ void k_scatter(const int* __restrict__ opArr, const int* __restrict__ off,
                          int* __restrict__ cur, int* __restrict__ rowIdx) {
    __shared__ int h[NOPS], bb[NOPS];
    int tid = threadIdx.x;
    if (tid < NOPS) h[tid] = 0;
    __syncthreads();
    int b = blockIdx.x * 256 + tid;
    int op = opArr[b];
    int my = atomicAdd(&h[op], 1);
    __syncthreads();
    if (tid < NOPS && h[tid] > 0) bb[tid] = atomicAdd(&cur[tid], h[tid]);
    __syncthreads();
    rowIdx[off[op] + bb[op] + my] = b;
}

// tileArr[g] = (op<<12)|tile (aliases opArr; stream order protects)
__global__ void k_tilemap(const int* __restrict__ cnt, const int* __restrict__ tb,
                          int* __restrict__ tileArr) {
    int o = blockIdx.x;
    int n = (cnt[o] + 3) >> 2, base = tb[o];
    for (int t = threadIdx.x; t < n; t += 64)
        tileArr[base + t] = (o << 12) | t;
}

// transpose one [R][C] fp32 matrix -> [C][R] bf16 (289 blocks)
__global__ void k_wt(const float* __restrict__ Wi1, const float* __restrict__ Wi2,
                     const float* __restrict__ Wq,  const float* __restrict__ Wk,
                     const float* __restrict__ Wv,
                     const float* __restrict__ Wc1, const float* __restrict__ Wc2,
                     const float* __restrict__ Wd1, const float* __restrict__ Wd2,
                     const float* __restrict__ Wm1, const float* __restrict__ Wm2,
                     const float* __restrict__ Wf1, const float* __restrict__ Wf2,
                     __bf16* __restrict__ wb) {
    __shared__ float t[8320];  // max R*(C+1) = 128*65
    int m = blockIdx.x;
    const float* src; __bf16* dst; int R, C;
    if      (m < 37)  { src = Wi1 + m * 8192;        dst = wb + OFF_WI1T + m * 8192;        R = 64;  C = 128; }
    else if (m < 74)  { src = Wi2 + (m-37) * 8192;   dst = wb + OFF_WI2T + (m-37) * 8192;   R = 128; C = 64;  }
    else if (m < 111) { src = Wc1 + (m-74) * 8192;   dst = wb + OFF_WC1T + (m-74) * 8192;   R = 64;  C = 128; }
    else if (m < 148) { src = Wc2 + (m-111) * 8192;  dst = wb + OFF_WC2T + (m-111) * 8192;  R = 128; C = 64;  }
    else if (m < 185) { src = Wf1 + (m-148) * 8192;  dst = wb + OFF_WF1T + (m-148) * 8192;  R = 64;  C = 128; }
    else if (m < 222) { src = Wf2 + (m-185) * 8192;  dst = wb + OFF_WF2T + (m-185) * 8192;  R = 128; C = 64;  }
    else if (m < 238) { src = Wd1 + (m-222) * 8192;  dst = wb + OFF_WD1T + (m-222) * 8192;  R = 64;  C = 128; }
    else if (m < 254) { src = Wd2 + (m-238) * 8192;  dst = wb + OFF_WD2T + (m-238) * 8192;  R = 128; C = 64;  }
    else if (m < 270) { src = Wm1 + (m-254) * 8192;  dst = wb + OFF_WM1T + (m-254) * 8192;  R = 64;  C = 128; }
    else if (m < 286) { src = Wm2 + (m-270) * 8192;  dst = wb + OFF_WM2T + (m-270) * 8192;  R = 128; C = 64;  }
    else { const float* q3[3] = {Wq, Wk, Wv}; src = q3[m-286]; dst = wb + OFF_QKVT + (m-286) * 4096; R = 64; C = 64; }
    int n = R * C, Cp = C + 1;
    int logC = (C == 128) ? 7 : 6, logR = (R == 128) ? 7 : 6;
    for (int i = threadIdx.x; i < n; i += 256)
        t[(i >> logC) * Cp + (i & (C - 1))] = src[i];
    __syncthreads();
    for (int o = threadIdx.x; o < n; o += 256) {
        int c = o >> logR, r = o & (R - 1);
        dst[o] = (__bf16)t[r * Cp + c];
    }
}

// ---------------- main kernel helpers ----------------

__device__ __forceinline__ bfrag zfrag() {
    bfrag r;
    #pragma unroll
    for (int j = 0; j < 8; ++j) r[j] = (__bf16)0.0f;
    return r;
}

__device__ __forceinline__ bhalf4 pack4(f32x4 a) {
    bhalf4 r;
    r[0] = (__bf16)a[0]; r[1] = (__bf16)a[1]; r[2] = (__bf16)a[2]; r[3] = (__bf16)a[3];
    return r;
}

__device__ __forceinline__ bhalf4 pack4f(float4 a) {
    bhalf4 r;
    r[0] = (__bf16)a.x; r[1] = (__bf16)a.y; r[2] = (__bf16)a.z; r[3] = (__bf16)a.w;
    return r;
}

__device__ __forceinline__ bhalf4 pack4_relu(f32x4 a) {
    bhalf4 r;
    r[0] = (__bf16)fmaxf(a[0], 0.0f); r[1] = (__bf16)fmaxf(a[1], 0.0f);
    r[2] = (__bf16)fmaxf(a[2], 0.0f); r[3] = (__bf16)fmaxf(a[3], 0.0f);
    return r;
}

// Cooperative FFN, swapped operands: D = W * X^T.
// Weight fragments + biases prefetched BEFORE the opening barrier.
// A-inputs read straight from the bf16 X mirror (no cvt on critical path).
__device__ __forceinline__ void ffn_coop(float* Xs, __bf16* Xb, __bf16* Hs,
    const __bf16* __restrict__ W1t, const float* __restrict__ b1,
    const __bf16* __restrict__ W2t, const float* __restrict__ b2,
    int w, int lq, int qd) {
    bfrag w1f[2][2], w2f[4];
    #pragma unroll
    for (int nt2 = 0; nt2 < 2; ++nt2)
        #pragma unroll
        for (int kf = 0; kf < 2; ++kf)
            w1f[nt2][kf] = *(const bfrag*)(W1t + ((w * 2 + nt2) * 16 + lq) * 64 + kf * 32 + qd * 8);
    #pragma unroll
    for (int kf = 0; kf < 4; ++kf)
        w2f[kf] = *(const bfrag*)(W2t + (w * 16 + lq) * 128 + kf * 32 + qd * 8);
    float4 b1v[2];
    b1v[0] = *(const float4*)(b1 + (w * 2 + 0) * 16 + qd * 4);
    b1v[1] = *(const float4*)(b1 + (w * 2 + 1) * 16 + qd * 4);
    float4 b2v = *(const float4*)(b2 + w * 16 + qd * 4);
    __syncthreads();
    {
        bfrag xa[2][2];
        #pragma unroll
        for (int mt = 0; mt < 2; ++mt)
            #pragma unroll
            for (int kf = 0; kf < 2; ++kf)
                xa[mt][kf] = *(const bfrag*)&Xb[(mt * 16 + lq) * 72 + kf * 32 + qd * 8];
        #pragma unroll
        for (int nt2 = 0; nt2 < 2; ++nt2) {
            int nt = w * 2 + nt2;
            f32x4 acc0 = {b1v[nt2].x, b1v[nt2].y, b1v[nt2].z, b1v[nt2].w}, acc1 = acc0;
            #pragma unroll
            for (int kf = 0; kf < 2; ++kf) {
                acc0 = MFMA16(w1f[nt2][kf], xa[0][kf], acc0);
                acc1 = MFMA16(w1f[nt2][kf], xa[1][kf], acc1);
            }
            // lane holds H[mt*16+lq][nt*16+qd*4 .. +3]
            *(bhalf4*)&Hs[lq * 136 + nt * 16 + qd * 4]        = pack4_relu(acc0);
            *(bhalf4*)&Hs[(16 + lq) * 136 + nt * 16 + qd * 4] = pack4_relu(acc1);
        }
    }
    __syncthreads();
    {
        f32x4 acc0 = {b2v.x, b2v.y, b2v.z, b2v.w}, acc1 = acc0;
        #pragma unroll
        for (int kf = 0; kf < 4; ++kf) {
            bfrag h0 = *(const bfrag*)&Hs[lq * 136 + kf * 32 + qd * 8];
            bfrag h1 = *(const bfrag*)&Hs[(16 + lq) * 136 + kf * 32 + qd * 8];
            acc0 = MFMA16(w2f[kf], h0, acc0);
            acc1 = MFMA16(w2f[kf], h1, acc1);
        }
        // lane holds Y[row][w*16+qd*4 .. +3] -> float4 RMW + bf16 mirror write
        float4* p0 = (float4*)&Xs[lq * 68 + w * 16 + qd * 4];
        float4 v0 = *p0;
        v0.x += acc0[0]; v0.y += acc0[1]; v0.z += acc0[2]; v0.w += acc0[3];
        *p0 = v0;
        *(bhalf4*)&Xb[lq * 72 + w * 16 + qd * 4] = pack4f(v0);
        float4* p1 = (float4*)&Xs[(16 + lq) * 68 + w * 16 + qd * 4];
        float4 v1 = *p1;
        v1.x += acc1[0]; v1.y += acc1[1]; v1.z += acc1[2]; v1.w += acc1[3];
        *p1 = v1;
        *(bhalf4*)&Xb[(16 + lq) * 72 + w * 16 + qd * 4] = pack4f(v1);
    }
}

// Cooperative attention. Waves {0,1} -> chunk 0 (rows 0..15), {2,3} -> chunk 1.
// Proj: 12 N-tiles split 6/6 within the wave pair (prefetched weights).
// FUSED scores+softmax+PV: each wave scores its own 8-row slot, writes its
// own Pb diag block, reads the pb fragment back wave-locally (lgkmcnt, no
// barrier — r9-validated), then PV over all 4 nt with the RMW predicated to
// its slot's rows. Partner-lane Pb garbage only feeds discarded D-columns.
__device__ __forceinline__ void attn_coop(float* Xs, __bf16* Xb, __bf16* Qb, __bf16* Kb,
    __bf16* VtT, __bf16* Pb, const __bf16* __restrict__ qkvt, int w, int lq, int qd) {
    int c = w >> 1, half = w & 1;
    bfrag wfp[6][2];
    #pragma unroll
    for (int i = 0; i < 6; ++i) {
        int nt = half * 6 + i;
        #pragma unroll
        for (int kf = 0; kf < 2; ++kf)
            wfp[i][kf] = *(const bfrag*)(qkvt + (nt * 16 + lq) * 64 + kf * 32 + qd * 8);
    }
    __syncthreads();
    {   // QKV projection: 12 N-tiles split 6/6 within the wave pair
        bfrag xa[2];
        #pragma unroll
        for (int kf = 0; kf < 2; ++kf)
            xa[kf] = *(const bfrag*)&Xb[(c * 16 + lq) * 72 + kf * 32 + qd * 8];
        int nt0 = half * 6;
        #pragma unroll
        for (int i = 0; i < 6; ++i) {
            int nt = nt0 + i;
            f32x4 acc = {0.f, 0.f, 0.f, 0.f};
            if (nt < 8) {
                #pragma unroll
                for (int kf = 0; kf < 2; ++kf)
                    acc = MFMA16(wfp[i][kf], xa[kf], acc);   // swapped: lane holds row lq, 4 ch
                __bf16* dst = (nt < 4)
                    ? &Qb[c * 1152 + lq * 72 + nt * 16 + qd * 4]
                    : &Kb[c * 1152 + lq * 72 + (nt - 4) * 16 + qd * 4];
                *(bhalf4*)dst = pack4(acc);
            } else {
                #pragma unroll
                for (int kf = 0; kf < 2; ++kf)
                    acc = MFMA16(xa[kf], wfp[i][kf], acc);   // unswapped: lane holds V[4 pos][d]
                // store V^T[d][p]: 4 consecutive p -> b64 (stride 24: 2-way banks)
                *(bhalf4*)&VtT[c * 1536 + ((nt - 8) * 16 + lq) * 24 + qd * 4] = pack4(acc);
            }
        }
    }
    __syncthreads();
    {   // FUSED: scores S = Q K^T / 8 for slot (c, half) + softmax + PV
        int qr = (half * 8 + lq) & 15;   // wrapped rows: garbage lanes discarded
        f32x4 sv = {0.f, 0.f, 0.f, 0.f};
        #pragma unroll
        for (int kf = 0; kf < 2; ++kf) {
            bfrag qa = *(const bfrag*)&Qb[c * 1152 + qr * 72 + kf * 32 + qd * 8];
            bfrag kb = *(const bfrag*)&Kb[c * 1152 + qr * 72 + kf * 32 + qd * 8];
            sv = MFMA16(qa, kb, sv);
        }
        // valid S at qd<2 (q-row qd*4+r), lq<8 (k-col); reduce across 8 k-lanes
        float p4[4];
        #pragma unroll
        for (int r = 0; r < 4; ++r) {
            float v = sv[r] * 0.125f;
            float m = v;
            m = fmaxf(m, __shfl_xor(m, 1));
            m = fmaxf(m, __shfl_xor(m, 2));
            m = fmaxf(m, __shfl_xor(m, 4));
            float e = __expf(v - m);
            float s = e;
            s += __shfl_xor(s, 1);
            s += __shfl_xor(s, 2);
            s += __shfl_xor(s, 4);
            p4[r] = e * __builtin_amdgcn_rcpf(s);
        }
        if (lq < 8 && qd < 2) {
            #pragma unroll
            for (int r = 0; r < 4; ++r)
                Pb[c * 256 + (half * 8 + qd * 4 + r) * 16 + half * 8 + lq] = (__bf16)p4[r];
        }
        // wave-local P read-back (no barrier): own-slot rows just written by
        // this wave; other-slot rows may be mid-write by the partner but feed
        // only D-columns we discard below.
        bfrag pb = (qd < 2) ? *(const bfrag*)&Pb[c * 256 + lq * 16 + qd * 8] : zfrag();
        #pragma unroll
        for (int nt = 0; nt < 4; ++nt) {
            bfrag va = (qd < 2) ? *(const bfrag*)&VtT[c * 1536 + (nt * 16 + lq) * 24 + qd * 8]
                                : zfrag();
            f32x4 z = {0.f, 0.f, 0.f, 0.f};
            f32x4 acc = MFMA16(va, pb, z);
            // lane holds O[row lq][nt*16+qd*4 .. +3]; RMW only our slot's rows
            if ((lq >> 3) == half) {
                float4* xp = (float4*)&Xs[(c * 16 + lq) * 68 + nt * 16 + qd * 4];
                float4 xv = *xp;
                xv.x += acc[0]; xv.y += acc[1]; xv.z += acc[2]; xv.w += acc[3];
                *xp = xv;
                *(bhalf4*)&Xb[(c * 16 + lq) * 72 + nt * 16 + qd * 4] = pack4f(xv);
            }
        }
    }
}

// ---------------- main kernel ----------------

__global__ void __launch_bounds__(256, 4)
moe_main(const float* __restrict__ x, float* __restrict__ out,
         const int* __restrict__ tileArr, const int* __restrict__ tb,
         const int* __restrict__ cnt, const int* __restrict__ off,
         const int* __restrict__ rowIdx, const __bf16* __restrict__ wb,
         const float* __restrict__ bi1, const float* __restrict__ bi2,
         const float* __restrict__ bc1, const float* __restrict__ bc2,
         const float* __restrict__ bd1, const float* __restrict__ bd2,
         const float* __restrict__ bm1, const float* __restrict__ bm2,
         const float* __restrict__ bf1_, const float* __restrict__ bf2_) {
    __shared__ float Xs[32 * 68];                  // 8704 B (fp32 state)
    __shared__ __bf16 Xb[32 * 72];                 // 4608 B (bf16 mirror of state)
    __shared__ __align__(16) unsigned char UB[16384];
    __bf16* Hs  = (__bf16*)UB;                     // [32][136] bf16 = 8704 B (FFN)
    __bf16* Qb  = (__bf16*)UB;                     // [2][16][72] = 4608 B (attn)
    __bf16* Kb  = (__bf16*)(UB + 4608);            // [2][16][72] = 4608 B
    __bf16* VtT = (__bf16*)(UB + 9216);            // [2][64][24] = 6144 B
    __bf16* Pb  = (__bf16*)(UB + 15360);           // [2][16][16] = 1024 B (block-diag,
                                                   //  outside Hs -> survives FFNs)
    int g = blockIdx.x;
    if (g >= tb[NOPS]) return;
    int v = tileArr[g];
    int op = v >> 12, tile = v & 4095;

    int tid = threadIdx.x;
    int w = tid >> 6, lane = tid & 63, lq = lane & 15, qd = lane >> 4;

    int base = off[op] + tile * 4;
    int nr = cnt[op] - tile * 4; if (nr > 4) nr = 4;
    int rows[4];
    #pragma unroll
    for (int s = 0; s < 4; ++s) rows[s] = rowIdx[base + (s < nr ? s : nr - 1)];

    bool carry = (op <= 2) || (op >= 10 && op <= 13);

    // load X (4 rows x 8 pos x 64 ch), float4-vectorized, dual-write fp32+bf16
    {
        int i0 = tid * 8;
        int m = i0 >> 6, d = i0 & 63;
        const float* srcp = x + (size_t)rows[m >> 3] * 512 + (m & 7) * 64 + d;
        float4 a = *(const float4*)srcp;
        float4 b = *(const float4*)(srcp + 4);
        *(float4*)&Xs[m * 68 + d]     = a;
        *(float4*)&Xs[m * 68 + d + 4] = b;
        *(bhalf4*)&Xb[m * 72 + d]     = pack4f(a);
        *(bhalf4*)&Xb[m * 72 + d + 4] = pack4f(b);
    }
    if (carry) {
        // one-time zero of Pb (off-diagonal stays zero; diag blocks rewritten
        // every iter; Pb sits outside Hs's 8704 B so it survives FFN phases)
        for (int i = tid; i < 512; i += 256) Pb[i] = (__bf16)0.0f;
    }
    // (ffn_coop opens with __syncthreads)

    // Stage 1: initial experts
    ffn_coop(Xs, Xb, Hs, wb + OFF_WI1T + op * 8192, bi1 + op * 128,
                         wb + OFF_WI2T + op * 8192, bi2 + op * 64, w, lq, qd);

    // Stages 2-3: carry cascade
    if (carry) {
        const __bf16* qkvt = wb + OFF_QKVT;
        for (int it = 0; it < 7; ++it) {
            attn_coop(Xs, Xb, Qb, Kb, VtT, Pb, qkvt, w, lq, qd);
            ffn_coop(Xs, Xb, Hs, wb + OFF_WC1T + op * 8192, bc1 + op * 128,
                                 wb + OFF_WC2T + op * 8192, bc2 + op * 64, w, lq, qd);
        }
    }
    // DIV / MOD iterative FFNs
    if (op == 3) {
        for (int i = 0; i < 16; ++i)
            ffn_coop(Xs, Xb, Hs, wb + OFF_WD1T + i * 8192, bd1 + i * 128,
                                 wb + OFF_WD2T + i * 8192, bd2 + i * 64, w, lq, qd);
    }
    if (op == 4) {
        for (int i = 0; i < 16; ++i)
            ffn_coop(Xs, Xb, Hs, wb + OFF_WM1T + i * 8192, bm1 + i * 128,
                                 wb + OFF_WM2T + i * 8192, bm2 + i * 64, w, lq, qd);
    }
    // Stage 4: final experts
    ffn_coop(Xs, Xb, Hs, wb + OFF_WF1T + op * 8192, bf1_ + op * 128,
                         wb + OFF_WF2T + op * 8192, bf2_ + op * 64, w, lq, qd);

    __syncthreads();
    for (int i = tid * 4; i < nr * 512; i += 1024) {
        int s = i >> 9, rem = i & 511;
        *(float4*)&out[(size_t)rows[s] * 512 + rem] =
            *(float4*)&Xs[(s * 8 + (rem >> 6)) * 68 + (rem & 63)];
    }
}

// ---------------- launch ----------------

extern "C" void kernel_launch(void* const* d_in, const int* in_sizes, int n_in,
                              void* d_out, int out_size, void* d_ws, size_t ws_size,
                              hipStream_t stream) {
    (void)in_sizes; (void)n_in; (void)out_size; (void)ws_size;
    const float* x   = (const float*)d_in[0];
    const float* Wi1 = (const float*)d_in[1];
    const float* bi1 = (const float*)d_in[2];
    const float* Wi2 = (const float*)d_in[3];
    const float* bi2 = (const float*)d_in[4];
    const float* Wq  = (const float*)d_in[5];
    const float* Wk  = (const float*)d_in[6];
    const float* Wv  = (const float*)d_in[7];
    const float* Wc1 = (const float*)d_in[8];
    const float* bc1 = (const float*)d_in[9];
    const float* Wc2 = (const float*)d_in[10];
    const float* bc2 = (const float*)d_in[11];
    const float* Wd1 = (const float*)d_in[12];
    const float* bd1 = (const float*)d_in[13];
    const float* Wd2 = (const float*)d_in[14];
    const float* bd2 = (const float*)d_in[15];
    const float* Wm1 = (const float*)d_in[16];
    const float* bm1 = (const float*)d_in[17];
    const float* Wm2 = (const float*)d_in[18];
    const float* bm2 = (const float*)d_in[19];
    const float* Wf1 = (const float*)d_in[20];
    const float* bf1 = (const float*)d_in[21];
    const float* Wf2 = (const float*)d_in[22];
    const float* bf2 = (const float*)d_in[23];
    float* out = (float*)d_out;

    int* wsi     = (int*)d_ws;
    int* opArr   = wsi + WS_OPARR;
    int* tileArr = wsi + WS_OPARR;   // alias: written after k_scatter consumes opArr
    int* cnt     = wsi + WS_CNT;
    int* off     = wsi + WS_OFF;
    int* cur     = wsi + WS_CUR;
    int* tb      = wsi + WS_TB;
    int* rowIdx  = wsi + WS_ROWIDX;
    __bf16* wb   = (__bf16*)((char*)d_ws + WS_INTS * 4);

    hipMemsetAsync((char*)d_ws + WS_CNT * 4, 0, NOPS * 4, stream);
    k_op<<<NB / 64, 64, 0, stream>>>(x, opArr, cnt);
    k_scan<<<1, 64, 0, stream>>>(cnt, off, tb, cur);
    k_scatter<<<NB / 256, 256, 0, stream>>>(opArr, off, cur, rowIdx);
    k_tilemap<<<NOPS, 64, 0, stream>>>(cnt, tb, tileArr);
    k_wt<<<289, 256, 0, stream>>>(Wi1, Wi2, Wq, Wk, Wv, Wc1, Wc2, Wd1, Wd2, Wm1, Wm2, Wf1, Wf2, wb);
    moe_main<<<NB / 4 + NOPS, 256, 0, stream>>>(x, out, tileArr, tb, cnt, off, rowIdx, wb,
                                                bi1, bi2, bc1, bc2, bd1, bd2, bm1, bm2, bf1, bf2);
}